// Round 10
// baseline (498.880 us; speedup 1.0000x reference)
//
#include <hip/hip_runtime.h>
#include <hip/hip_bf16.h>

#define TPB 256

typedef __attribute__((ext_vector_type(8))) short bf16x8;
typedef __attribute__((ext_vector_type(4))) float f32x4;

static __device__ __forceinline__ unsigned short f2bf(float f) {
  union { float f; unsigned int u; } x; x.f = f;
  unsigned int r = x.u + 0x7FFF + ((x.u >> 16) & 1);   // RNE
  return (unsigned short)(r >> 16);
}
static __device__ __forceinline__ float bf2f(unsigned short h) {
  union { unsigned int u; float f; } x; x.u = ((unsigned int)h) << 16;
  return x.f;
}

#define MFMA16(a, b, c) __builtin_amdgcn_mfma_f32_16x16x32_bf16(a, b, c, 0, 0, 0)

// ---------------------------------------------------------------------------
// Augmented fold GEMM (unchanged from round 9).
// ---------------------------------------------------------------------------
__global__ __launch_bounds__(TPB) void gemm_fold_k(
    const float* __restrict__ A, const float* __restrict__ lastrow,
    const float* __restrict__ W, const float* __restrict__ bias,
    float* __restrict__ C, unsigned short* __restrict__ WfTh,
    unsigned short* __restrict__ WfTl, float* __restrict__ bfv,
    int K, int Nc, int mode)
{
  __shared__ float As[16][68];
  __shared__ float Ws[16][68];
  int tid = threadIdx.x;
  int col0 = blockIdx.x * 64;
  int ty = tid >> 4, tx = tid & 15;
  float acc[4][4] = {};
  for (int k0 = 0; k0 < K; k0 += 16) {
#pragma unroll
    for (int i = 0; i < 4; ++i) {
      int idx = tid + i * 256;
      int r = idx >> 4, kk = idx & 15;
      int gk = k0 + kk;
      float v = 0.f;
      if (gk < K) {
        if (r < 50) v = A[(size_t)r * K + gk];
        else if (r == 50) v = lastrow[gk];
      }
      As[kk][r] = v;
    }
#pragma unroll
    for (int i = 0; i < 4; ++i) {
      int idx = tid + i * 256;
      int c = idx & 63, kk = idx >> 6;
      int gc = col0 + c, gk = k0 + kk;
      float v = 0.f;
      if (gk < K && gc < Nc) v = W[(size_t)gk * Nc + gc];
      Ws[kk][c] = v;
    }
    __syncthreads();
#pragma unroll
    for (int kk = 0; kk < 16; ++kk) {
      float4 a4 = *(const float4*)&As[kk][ty * 4];
      float4 b4 = *(const float4*)&Ws[kk][tx * 4];
      float av[4] = {a4.x, a4.y, a4.z, a4.w};
      float bv[4] = {b4.x, b4.y, b4.z, b4.w};
#pragma unroll
      for (int i = 0; i < 4; ++i)
#pragma unroll
        for (int j = 0; j < 4; ++j)
          acc[i][j] = fmaf(av[i], bv[j], acc[i][j]);
    }
    __syncthreads();
  }
#pragma unroll
  for (int i = 0; i < 4; ++i) {
    int gr = ty * 4 + i;
#pragma unroll
    for (int j = 0; j < 4; ++j) {
      int gc = col0 + tx * 4 + j;
      if (gc >= Nc) continue;
      float v = acc[i][j];
      if (gr == 50) v += bias[gc];
      if (mode == 0) {
        if (gr < 51) C[(size_t)gr * Nc + gc] = v;
      } else {
        if (gr == 50) bfv[gc] = v;
        else {
          unsigned short hi = f2bf(v);
          size_t el = (size_t)gc * 64 + (gr ^ ((gc & 7) * 8));
          WfTh[el] = hi;
          WfTl[el] = f2bf(v - bf2f(hi));
        }
      }
    }
  }
}

// ---------------------------------------------------------------------------
// Split-precision MFMA ruv GEMM, v2:
//  - rows blocked by (b, nb): m0 = b*961 + nb*64 -> Vt n0 always 4-aligned
//  - x tile staged coalesced into padded LDS; fragments built from LDS
// Grid (9, 128). Col blocks 0..5 -> RU, 6..8 -> Vt.
// ---------------------------------------------------------------------------
__global__ __launch_bounds__(TPB) void gemm_ruv_mfma_k(
    const float* __restrict__ x,              // [7688][50]
    const unsigned short* __restrict__ WfTh,  // [2304][64] bf16 swizzled
    const unsigned short* __restrict__ WfTl,  // [2304][64] bf16 swizzled
    const float* __restrict__ bias,           // [2304] fp32
    unsigned short* __restrict__ RU,          // [7688][1536]
    unsigned short* __restrict__ Vt)          // [hb][64][968], hb=h*8+b
{
  __shared__ unsigned short Bl[256 * 64];     // 32 KB
  __shared__ float Xs[64][68];                // 17.4 KB, padded (2-way max)
  int tid = threadIdx.x, w = tid >> 6, lane = tid & 63;
  int g = lane >> 4, c = lane & 15;
  int by = blockIdx.y;                        // 0..127
  int b = by >> 4, nb = by & 15;
  int m0 = b * 961 + nb * 64;
  int n0base = nb * 64;
  int col0 = blockIdx.x * 256;
  int wc0 = w * 64;

  // ---- stage x tile coalesced (cols 50..63 zero) ----
#pragma unroll
  for (int i = 0; i < 16; ++i) {
    int idx = tid + i * 256;                  // 0..4095
    int row = idx >> 6, cc = idx & 63;
    int grow = m0 + row;
    float v = 0.f;
    if (cc < 50 && grow < 7688) v = x[(size_t)grow * 50 + cc];
    Xs[row][cc] = v;
  }

  // ---- stage B = Wf_hi ----
#pragma unroll
  for (int it = 0; it < 8; ++it) {
    int chunk = tid + it * 256;
    int colr = chunk >> 3, s = chunk & 7;
    *(int4*)&Bl[colr * 64 + s * 8] =
        *(const int4*)&WfTh[(size_t)(col0 + colr) * 64 + s * 8];
  }
  __syncthreads();

  // ---- build hi/lo A fragments from LDS ----
  bf16x8 afh[4][2], afl[4][2];
#pragma unroll
  for (int rt = 0; rt < 4; ++rt) {
    int lrow = rt * 16 + c;
#pragma unroll
    for (int kk = 0; kk < 2; ++kk) {
      float4 v0 = *(const float4*)&Xs[lrow][kk * 32 + g * 8];
      float4 v1 = *(const float4*)&Xs[lrow][kk * 32 + g * 8 + 4];
      float vv[8] = {v0.x, v0.y, v0.z, v0.w, v1.x, v1.y, v1.z, v1.w};
      bf16x8 ah, al;
#pragma unroll
      for (int i = 0; i < 8; ++i) {
        unsigned short hi = f2bf(vv[i]);
        ah[i] = (short)hi;
        al[i] = (short)f2bf(vv[i] - bf2f(hi));
      }
      afh[rt][kk] = ah;
      afl[rt][kk] = al;
    }
  }

  f32x4 zero4 = {0.f, 0.f, 0.f, 0.f};
  f32x4 acc[4][4] = {{zero4, zero4, zero4, zero4}, {zero4, zero4, zero4, zero4},
                     {zero4, zero4, zero4, zero4}, {zero4, zero4, zero4, zero4}};

  // ---- pass 1: (x_hi + x_lo) @ Wf_hi ----
#pragma unroll
  for (int ct = 0; ct < 4; ++ct) {
    int bcol = wc0 + ct * 16 + c;
    int sw = (bcol & 7) * 8;
    bf16x8 b0 = *(const bf16x8*)&Bl[bcol * 64 + ((g * 8) ^ sw)];
    bf16x8 b1 = *(const bf16x8*)&Bl[bcol * 64 + ((32 + g * 8) ^ sw)];
#pragma unroll
    for (int rt = 0; rt < 4; ++rt) {
      acc[rt][ct] = MFMA16(afh[rt][0], b0, acc[rt][ct]);
      acc[rt][ct] = MFMA16(afh[rt][1], b1, acc[rt][ct]);
      acc[rt][ct] = MFMA16(afl[rt][0], b0, acc[rt][ct]);
      acc[rt][ct] = MFMA16(afl[rt][1], b1, acc[rt][ct]);
    }
  }
  __syncthreads();

  // ---- stage B = Wf_lo ----
#pragma unroll
  for (int it = 0; it < 8; ++it) {
    int chunk = tid + it * 256;
    int colr = chunk >> 3, s = chunk & 7;
    *(int4*)&Bl[colr * 64 + s * 8] =
        *(const int4*)&WfTl[(size_t)(col0 + colr) * 64 + s * 8];
  }
  __syncthreads();

  // ---- pass 2: x_hi @ Wf_lo ----
#pragma unroll
  for (int ct = 0; ct < 4; ++ct) {
    int bcol = wc0 + ct * 16 + c;
    int sw = (bcol & 7) * 8;
    bf16x8 b0 = *(const bf16x8*)&Bl[bcol * 64 + ((g * 8) ^ sw)];
    bf16x8 b1 = *(const bf16x8*)&Bl[bcol * 64 + ((32 + g * 8) ^ sw)];
#pragma unroll
    for (int rt = 0; rt < 4; ++rt) {
      acc[rt][ct] = MFMA16(afh[rt][0], b0, acc[rt][ct]);
      acc[rt][ct] = MFMA16(afh[rt][1], b1, acc[rt][ct]);
    }
  }

  // ---- epilogue ----
  bool isRU = (col0 < 1536);
#pragma unroll
  for (int ct = 0; ct < 4; ++ct) {
    int col = col0 + wc0 + ct * 16 + c;
    float bs = bias[col];
    if (isRU) {
#pragma unroll
      for (int rt = 0; rt < 4; ++rt) {
        int lr0 = rt * 16 + g * 4;
#pragma unroll
        for (int r = 0; r < 4; ++r) {
          int n = n0base + lr0 + r;
          if (n <= 960)
            RU[(size_t)(m0 + lr0 + r) * 1536 + col] = f2bf(acc[rt][ct][r] + bs);
        }
      }
    } else {
      int hd = col - 1536;
      int hh = hd >> 6, d = hd & 63;
      size_t vrow = ((size_t)(hh * 8 + b) * 64 + d) * 968;
#pragma unroll
      for (int rt = 0; rt < 4; ++rt) {
        int n0 = n0base + rt * 16 + g * 4;    // always 4-aligned
        if (n0 + 3 <= 960) {
          ushort4 o;
          o.x = f2bf(acc[rt][ct][0] + bs);
          o.y = f2bf(acc[rt][ct][1] + bs);
          o.z = f2bf(acc[rt][ct][2] + bs);
          o.w = f2bf(acc[rt][ct][3] + bs);
          *(ushort4*)&Vt[vrow + n0] = o;
        } else {
#pragma unroll
          for (int r = 0; r < 4; ++r) {
            int n = n0 + r;
            if (n <= 960) Vt[vrow + n] = f2bf(acc[rt][ct][r] + bs);
          }
        }
      }
    }
  }
}

// ---------------------------------------------------------------------------
// Fused heterogeneous kernel: attention + fold_wp (unchanged from round 9).
// ---------------------------------------------------------------------------
__global__ __launch_bounds__(512) void attn_wp_k(
    const unsigned short* __restrict__ RU,
    const unsigned short* __restrict__ Vt,
    float* __restrict__ O,
    const float* __restrict__ Wp1, const float* __restrict__ Wp2,
    float* __restrict__ wfold)
{
  __shared__ unsigned short sh[24576];       // 48 KB
  int bid = blockIdx.x;
  int tid = threadIdx.x;

  if ((bid % 11) != 0) {
    float* w2 = (float*)sh;
    for (int i = tid; i < 1536; i += 512) w2[i] = Wp2[i];
    __syncthreads();
    int fid = bid - bid / 11 - 1;
    int wv = tid >> 6, lane = tid & 63;
    for (int m8 = fid; m8 < 7688; m8 += 7680) {
      int m = m8 * 8 + wv;
      const float* row = Wp1 + (size_t)m * 1536;
      float s = 0.f;
#pragma unroll
      for (int k = 0; k < 6; ++k) {
        float4 a  = *(const float4*)(row + k * 256 + lane * 4);
        float4 ww = *(const float4*)&w2[k * 256 + lane * 4];
        s += a.x * ww.x + a.y * ww.y + a.z * ww.z + a.w * ww.w;
      }
#pragma unroll
      for (int off2 = 32; off2 >= 1; off2 >>= 1) s += __shfl_xor(s, off2, 64);
      if (lane == 0) wfold[m] = s;
    }
    return;
  }

  const int NS = 961, RS = 1536, VROW = 968;
  int aid = bid / 11;
  int qb = aid & 7, hb = aid >> 3;
  int h = hb >> 3, b = hb & 7;
  int n0 = qb * 128;
  int w = tid >> 6, lane = tid & 63;
  int g = lane >> 4, c = lane & 15;
  const unsigned short* rubase = RU + (size_t)b * NS * RS;
  int roff = h * 64, uoff = 768 + h * 64;
  const unsigned short* vtbase = Vt + (size_t)hb * 64 * VROW;
  unsigned short* Kbuf[2] = {sh, sh + 4096};
  unsigned short* Vbuf[2] = {sh + 8192, sh + 12288};
  unsigned short* pw = sh + 16384 + w * 1024;

  int qrow = n0 + w * 16 + c;
  if (qrow > 960) qrow = 960;
  bf16x8 qf0 = *(const bf16x8*)(rubase + (size_t)qrow * RS + roff + g * 8);
  bf16x8 qf1 = *(const bf16x8*)(rubase + (size_t)qrow * RS + roff + 32 + g * 8);

  int srow = tid >> 3, ss = tid & 7;
  int sel = srow * 64 + 8 * (ss ^ (srow & 7));
  const unsigned short* ksrc = rubase + uoff + ss * 8;
  const unsigned short* vsrc = vtbase + (size_t)srow * VROW + ss * 8;

  {
    int4 kv = *(const int4*)(ksrc + (size_t)srow * RS);
    int4 vv = *(const int4*)(vsrc);
    *(int4*)&Kbuf[0][sel] = kv;
    *(int4*)&Vbuf[0][sel] = vv;
  }
  __syncthreads();

  f32x4 zero4 = {0.f, 0.f, 0.f, 0.f};
  f32x4 oacc[4] = {zero4, zero4, zero4, zero4};
  float rowsum[4] = {0.f, 0.f, 0.f, 0.f};

  unsigned short* Kc = Kbuf[0];
  unsigned short* Vc = Vbuf[0];
  unsigned short* Kn = Kbuf[1];
  unsigned short* Vn = Vbuf[1];

  for (int kt = 0; kt < 16; ++kt) {
    int4 pk, pv;
    bool pre = (kt < 15);
    if (pre) {
      int keyg = (kt + 1) * 64 + srow;
      int kcl = keyg > 960 ? 960 : keyg;
      pk = *(const int4*)(ksrc + (size_t)kcl * RS);
      pv = *(const int4*)(vsrc + (kt + 1) * 64);
    }

    f32x4 sa[4] = {zero4, zero4, zero4, zero4};
    __builtin_amdgcn_s_setprio(1);
#pragma unroll
    for (int ct = 0; ct < 4; ++ct) {
      int key = c * 4 + ct;
      int sw = (key & 7) * 8;
      bf16x8 k0 = *(const bf16x8*)&Kc[key * 64 + ((g * 8) ^ sw)];
      bf16x8 k1 = *(const bf16x8*)&Kc[key * 64 + ((32 + g * 8) ^ sw)];
      sa[ct] = MFMA16(qf0, k0, sa[ct]);
      sa[ct] = MFMA16(qf1, k1, sa[ct]);
    }
    __builtin_amdgcn_s_setprio(0);

#pragma unroll
    for (int r = 0; r < 4; ++r) {
      unsigned short pb[4];
#pragma unroll
      for (int ct = 0; ct < 4; ++ct) {
        int keyg = kt * 64 + c * 4 + ct;
        unsigned short p16 = 0;
        if (keyg <= 960) p16 = f2bf(__expf(sa[ct][r]));
        pb[ct] = p16;
        rowsum[r] += bf2f(p16);
      }
      int q = g * 4 + r;
      int e0 = (c * 4) ^ ((q & 7) * 8);
      *(unsigned int*)&pw[q * 64 + e0] =
          (unsigned int)pb[0] | ((unsigned int)pb[1] << 16);
      *(unsigned int*)&pw[q * 64 + e0 + 2] =
          (unsigned int)pb[2] | ((unsigned int)pb[3] << 16);
    }

    if (pre) {
      *(int4*)&Kn[sel] = pk;
      *(int4*)&Vn[sel] = pv;
    }

    __builtin_amdgcn_s_setprio(1);
#pragma unroll
    for (int kk = 0; kk < 2; ++kk) {
      bf16x8 pa = *(const bf16x8*)&pw[c * 64 + ((kk * 32 + g * 8) ^ ((c & 7) * 8))];
#pragma unroll
      for (int dt = 0; dt < 4; ++dt) {
        int d = dt * 16 + c;
        bf16x8 vf = *(const bf16x8*)&Vc[d * 64 + ((kk * 32 + g * 8) ^ ((d & 7) * 8))];
        oacc[dt] = MFMA16(pa, vf, oacc[dt]);
      }
    }
    __builtin_amdgcn_s_setprio(0);

    __syncthreads();
    unsigned short* t;
    t = Kc; Kc = Kn; Kn = t;
    t = Vc; Vc = Vn; Vn = t;
  }

#pragma unroll
  for (int r = 0; r < 4; ++r) {
    float s = rowsum[r];
    s += __shfl_xor(s, 1, 64);
    s += __shfl_xor(s, 2, 64);
    s += __shfl_xor(s, 4, 64);
    s += __shfl_xor(s, 8, 64);
    rowsum[r] = 1.f / s;
  }
  int nbase = n0 + w * 16 + g * 4;
  float* ob = O + (size_t)hb * 61504;
#pragma unroll
  for (int r = 0; r < 4; ++r) {
    int n = nbase + r;
    if (n > 960) continue;
#pragma unroll
    for (int dt = 0; dt < 4; ++dt)
      ob[(size_t)n * 64 + dt * 16 + c] = oacc[dt][r] * rowsum[r];
  }
}

// ---------------------------------------------------------------------------
// out[b*12+h] = O[hb,:] . wfold + bp1 . Wp2 + bp2
// ---------------------------------------------------------------------------
__global__ __launch_bounds__(TPB) void final_k(
    const float* __restrict__ O, const float* __restrict__ wfold,
    const float* __restrict__ bp1, const float* __restrict__ Wp2,
    const float* __restrict__ bp2, float* __restrict__ out)
{
  int hb = blockIdx.x;
  int h = hb >> 3, b = hb & 7;
  int tid = threadIdx.x;
  const float* orow = O + (size_t)hb * 61504;
  float s = 0.f;
  for (int i4 = tid; i4 < 15376; i4 += 256) {
    float4 a = *(const float4*)(orow + (size_t)i4 * 4);
    float4 w = *(const float4*)(wfold + (size_t)i4 * 4);
    s += a.x * w.x + a.y * w.y + a.z * w.z + a.w * w.w;
  }
  for (int p = tid; p < 1536; p += 256) s += bp1[p] * Wp2[p];
#pragma unroll
  for (int off = 32; off >= 1; off >>= 1) s += __shfl_xor(s, off, 64);
  __shared__ float red[4];
  if ((tid & 63) == 0) red[tid >> 6] = s;
  __syncthreads();
  if (tid == 0) out[b * 12 + h] = red[0] + red[1] + red[2] + red[3] + bp2[0];
}

// ---------------------------------------------------------------------------
extern "C" void kernel_launch(void* const* d_in, const int* in_sizes, int n_in,
                              void* d_out, int out_size, void* d_ws, size_t ws_size,
                              hipStream_t stream)
{
  const float* x    = (const float*)d_in[0];
  const float* W1   = (const float*)d_in[1];
  const float* b1   = (const float*)d_in[2];
  const float* W2   = (const float*)d_in[3];
  const float* b2   = (const float*)d_in[4];
  const float* W3   = (const float*)d_in[5];
  const float* b3   = (const float*)d_in[6];
  const float* W4   = (const float*)d_in[7];
  const float* b4   = (const float*)d_in[8];
  const float* Wruv = (const float*)d_in[9];
  const float* bruv = (const float*)d_in[10];
  const float* Wp1  = (const float*)d_in[11];
  const float* bp1  = (const float*)d_in[12];
  const float* Wp2  = (const float*)d_in[13];
  const float* bp2  = (const float*)d_in[14];
  float* out = (float*)d_out;

  char* base = (char*)d_ws;
  size_t off = 0;
  auto alloc = [&](size_t bytes) -> void* {
    void* p = base + off;
    off = (off + bytes + 255) & ~(size_t)255;
    return p;
  };
  unsigned short* RU  = (unsigned short*)alloc((size_t)7688 * 1536 * 2);          // 23.6 MB
  unsigned short* Vt  = (unsigned short*)alloc((size_t)96 * 64 * 968 * 2 + 1024); // 11.9 MB
  float* Ob    = (float*)alloc((size_t)96 * 61504 * 4);                           // 23.6 MB
  float* aug1  = (float*)alloc(51 * 200 * 4);
  float* aug2  = (float*)alloc(51 * 200 * 4);
  float* aug3  = (float*)alloc(51 * 768 * 4);
  unsigned short* WfTh = (unsigned short*)alloc((size_t)2304 * 64 * 2);
  unsigned short* WfTl = (unsigned short*)alloc((size_t)2304 * 64 * 2);
  float* bfv   = (float*)alloc(2304 * 4);
  float* wfold = (float*)alloc(61504 * 4);
  if (off > ws_size) return;

  dim3 tb(TPB);

  // ---- fold MLP+RUV into augmented [Wf; bf] via 4 GEMMs ----
  gemm_fold_k<<<dim3(4),  tb, 0, stream>>>(W1,   b1,            W2,   b2,   aug1,    nullptr, nullptr, nullptr, 200, 200, 0);
  gemm_fold_k<<<dim3(4),  tb, 0, stream>>>(aug1, aug1 + 50*200, W3,   b3,   aug2,    nullptr, nullptr, nullptr, 200, 200, 0);
  gemm_fold_k<<<dim3(12), tb, 0, stream>>>(aug2, aug2 + 50*200, W4,   b4,   aug3,    nullptr, nullptr, nullptr, 200, 768, 0);
  gemm_fold_k<<<dim3(36), tb, 0, stream>>>(aug3, aug3 + 50*768, Wruv, bruv, nullptr, WfTh,    WfTl,    bfv,     768, 2304, 1);

  // ---- ruv = x @ Wf + bf (split-bf16 MFMA, v2) -> RU + transposed Vt ----
  gemm_ruv_mfma_k<<<dim3(9, 128), tb, 0, stream>>>(x, WfTh, WfTl, bfv, RU, Vt);

  // ---- fused: MFMA flash attention (768 blocks) + Wp1@Wp2 fold (7680) ----
  attn_wp_k<<<dim3(8448), dim3(512), 0, stream>>>(RU, Vt, Ob, Wp1, Wp2, wfold);

  // ---- final scalar per (h,b) ----
  final_k<<<dim3(96), tb, 0, stream>>>(Ob, wfold, bp1, Wp2, bp2, out);
}

// Round 11
// 407.277 us; speedup vs baseline: 1.2249x; 1.2249x over previous
//
#include <hip/hip_runtime.h>
#include <hip/hip_bf16.h>

#define TPB 256

typedef __attribute__((ext_vector_type(8))) short bf16x8;
typedef __attribute__((ext_vector_type(4))) float f32x4;

static __device__ __forceinline__ unsigned short f2bf(float f) {
  union { float f; unsigned int u; } x; x.f = f;
  unsigned int r = x.u + 0x7FFF + ((x.u >> 16) & 1);   // RNE
  return (unsigned short)(r >> 16);
}
static __device__ __forceinline__ float bf2f(unsigned short h) {
  union { unsigned int u; float f; } x; x.u = ((unsigned int)h) << 16;
  return x.f;
}

#define MFMA16(a, b, c) __builtin_amdgcn_mfma_f32_16x16x32_bf16(a, b, c, 0, 0, 0)

// ---------------------------------------------------------------------------
// Augmented fold GEMM, fp32 out (stages 1-3): C(51,Nc) = [A;lastrow] @ W,
// bias added to row 50 only.
// ---------------------------------------------------------------------------
__global__ __launch_bounds__(TPB) void gemm_fold_k(
    const float* __restrict__ A, const float* __restrict__ lastrow,
    const float* __restrict__ W, const float* __restrict__ bias,
    float* __restrict__ C, int K, int Nc)
{
  __shared__ float As[16][68];
  __shared__ float Ws[16][68];
  int tid = threadIdx.x;
  int col0 = blockIdx.x * 64;
  int ty = tid >> 4, tx = tid & 15;
  float acc[4][4] = {};
  for (int k0 = 0; k0 < K; k0 += 16) {
#pragma unroll
    for (int i = 0; i < 4; ++i) {
      int idx = tid + i * 256;
      int r = idx >> 4, kk = idx & 15;
      int gk = k0 + kk;
      float v = 0.f;
      if (gk < K) {
        if (r < 50) v = A[(size_t)r * K + gk];
        else if (r == 50) v = lastrow[gk];
      }
      As[kk][r] = v;
    }
#pragma unroll
    for (int i = 0; i < 4; ++i) {
      int idx = tid + i * 256;
      int c = idx & 63, kk = idx >> 6;
      int gc = col0 + c, gk = k0 + kk;
      float v = 0.f;
      if (gk < K && gc < Nc) v = W[(size_t)gk * Nc + gc];
      Ws[kk][c] = v;
    }
    __syncthreads();
#pragma unroll
    for (int kk = 0; kk < 16; ++kk) {
      float4 a4 = *(const float4*)&As[kk][ty * 4];
      float4 b4 = *(const float4*)&Ws[kk][tx * 4];
      float av[4] = {a4.x, a4.y, a4.z, a4.w};
      float bv[4] = {b4.x, b4.y, b4.z, b4.w};
#pragma unroll
      for (int i = 0; i < 4; ++i)
#pragma unroll
        for (int j = 0; j < 4; ++j)
          acc[i][j] = fmaf(av[i], bv[j], acc[i][j]);
    }
    __syncthreads();
  }
#pragma unroll
  for (int i = 0; i < 4; ++i) {
    int gr = ty * 4 + i;
    if (gr >= 51) continue;
#pragma unroll
    for (int j = 0; j < 4; ++j) {
      int gc = col0 + tx * 4 + j;
      if (gc >= Nc) continue;
      float v = acc[i][j];
      if (gr == 50) v += bias[gc];
      C[(size_t)gr * Nc + gc] = v;
    }
  }
}

// ---------------------------------------------------------------------------
// Fused stage4 + x-prep kernel. Grid 157 blocks:
//  blocks 0..35  : stage4 GEMM [aug3(51x768)] @ Wruv -> WfTh/WfTl (LINEAR
//                  [col][64] bf16 split) + bfv (row 50 + bruv, fp32)
//  blocks 36..156: x split-precision prep: xh/xl [row][64] bf16 (cols 50..63
//                  zeroed), 64 rows per block.
// ---------------------------------------------------------------------------
__global__ __launch_bounds__(TPB) void fold4_xprep_k(
    const float* __restrict__ aug3,   // [51][768]
    const float* __restrict__ Wruv,   // [768][2304]
    const float* __restrict__ bruv,   // [2304]
    unsigned short* __restrict__ WfTh, unsigned short* __restrict__ WfTl,
    float* __restrict__ bfv,
    const float* __restrict__ x,      // [7688][50]
    unsigned short* __restrict__ xh, unsigned short* __restrict__ xl)
{
  __shared__ float As[16][68];
  __shared__ float Ws[16][68];
  int bid = blockIdx.x;
  int tid = threadIdx.x;

  if (bid >= 36) {
    // ---------------- x-prep role ----------------
    int row0 = (bid - 36) * 64;
#pragma unroll
    for (int i = 0; i < 16; ++i) {
      int idx = tid + i * 256;
      int row = row0 + (idx >> 6), cc = idx & 63;
      if (row >= 7688) continue;
      float v = (cc < 50) ? x[(size_t)row * 50 + cc] : 0.f;
      unsigned short hi = f2bf(v);
      xh[(size_t)row * 64 + cc] = hi;
      xl[(size_t)row * 64 + cc] = f2bf(v - bf2f(hi));
    }
    return;
  }

  // ---------------- stage4 GEMM role ----------------
  const int K = 768, Nc = 2304;
  const float* lastrow = aug3 + (size_t)50 * 768;
  int col0 = bid * 64;
  int ty = tid >> 4, tx = tid & 15;
  float acc[4][4] = {};
  for (int k0 = 0; k0 < K; k0 += 16) {
#pragma unroll
    for (int i = 0; i < 4; ++i) {
      int idx = tid + i * 256;
      int r = idx >> 4, kk = idx & 15;
      int gk = k0 + kk;
      float v = 0.f;
      if (r < 50) v = aug3[(size_t)r * K + gk];
      else if (r == 50) v = lastrow[gk];
      As[kk][r] = v;
    }
#pragma unroll
    for (int i = 0; i < 4; ++i) {
      int idx = tid + i * 256;
      int c = idx & 63, kk = idx >> 6;
      Ws[kk][c] = Wruv[(size_t)(k0 + kk) * Nc + col0 + c];
    }
    __syncthreads();
#pragma unroll
    for (int kk = 0; kk < 16; ++kk) {
      float4 a4 = *(const float4*)&As[kk][ty * 4];
      float4 b4 = *(const float4*)&Ws[kk][tx * 4];
      float av[4] = {a4.x, a4.y, a4.z, a4.w};
      float bv[4] = {b4.x, b4.y, b4.z, b4.w};
#pragma unroll
      for (int i = 0; i < 4; ++i)
#pragma unroll
        for (int j = 0; j < 4; ++j)
          acc[i][j] = fmaf(av[i], bv[j], acc[i][j]);
    }
    __syncthreads();
  }
#pragma unroll
  for (int i = 0; i < 4; ++i) {
    int gr = ty * 4 + i;
    if (gr >= 51) continue;
#pragma unroll
    for (int j = 0; j < 4; ++j) {
      int gc = col0 + tx * 4 + j;
      float v = acc[i][j];
      if (gr == 50) {
        bfv[gc] = v + bruv[gc];
      } else {
        unsigned short hi = f2bf(v);
        size_t el = (size_t)gc * 64 + gr;       // LINEAR layout
        WfTh[el] = hi;
        WfTl[el] = f2bf(v - bf2f(hi));
      }
    }
  }
}

// ---------------------------------------------------------------------------
// Split-precision MFMA ruv GEMM v3 — no LDS, no barriers.
// A fragments from xh/xl (bf16 [row][64], padded); B fragments from linear
// WfTh/WfTl (bf16 [col][64], L2-hot 288 KB). x_hi@W_hi + x_lo@W_hi + x_hi@W_lo.
// Rows blocked (b, nb): m0 = b*961 + nb*64 -> Vt n always 4-aligned.
// Grid (9, 128), 256 threads. Col blocks 0..5 -> RU, 6..8 -> Vt.
// ---------------------------------------------------------------------------
__global__ __launch_bounds__(TPB) void gemm_ruv_mfma_k(
    const unsigned short* __restrict__ xh,    // [7688+64][64] bf16
    const unsigned short* __restrict__ xl,
    const unsigned short* __restrict__ WfTh,  // [2304][64] bf16 linear
    const unsigned short* __restrict__ WfTl,
    const float* __restrict__ bias,           // [2304] fp32
    unsigned short* __restrict__ RU,          // [7688][1536]
    unsigned short* __restrict__ Vt)          // [hb][64][968], hb=h*8+b
{
  int tid = threadIdx.x, w = tid >> 6, lane = tid & 63;
  int g = lane >> 4, c = lane & 15;
  int by = blockIdx.y;
  int b = by >> 4, nb = by & 15;
  int m0 = b * 961 + nb * 64;
  int n0base = nb * 64;
  int col0 = blockIdx.x * 256;
  int wc0 = w * 64;

  // ---- A fragments hi/lo straight from global ----
  bf16x8 afh[4][2], afl[4][2];
#pragma unroll
  for (int rt = 0; rt < 4; ++rt) {
    size_t rowb = (size_t)(m0 + rt * 16 + c) * 64;
#pragma unroll
    for (int kk = 0; kk < 2; ++kk) {
      afh[rt][kk] = *(const bf16x8*)&xh[rowb + kk * 32 + g * 8];
      afl[rt][kk] = *(const bf16x8*)&xl[rowb + kk * 32 + g * 8];
    }
  }

  f32x4 zero4 = {0.f, 0.f, 0.f, 0.f};
  f32x4 acc[4][4] = {{zero4, zero4, zero4, zero4}, {zero4, zero4, zero4, zero4},
                     {zero4, zero4, zero4, zero4}, {zero4, zero4, zero4, zero4}};

#pragma unroll
  for (int ct = 0; ct < 4; ++ct) {
    size_t bcolb = (size_t)(col0 + wc0 + ct * 16 + c) * 64;
    bf16x8 bh0 = *(const bf16x8*)&WfTh[bcolb + g * 8];
    bf16x8 bh1 = *(const bf16x8*)&WfTh[bcolb + 32 + g * 8];
    bf16x8 bl0 = *(const bf16x8*)&WfTl[bcolb + g * 8];
    bf16x8 bl1 = *(const bf16x8*)&WfTl[bcolb + 32 + g * 8];
#pragma unroll
    for (int rt = 0; rt < 4; ++rt) {
      acc[rt][ct] = MFMA16(afh[rt][0], bh0, acc[rt][ct]);
      acc[rt][ct] = MFMA16(afh[rt][1], bh1, acc[rt][ct]);
      acc[rt][ct] = MFMA16(afl[rt][0], bh0, acc[rt][ct]);
      acc[rt][ct] = MFMA16(afl[rt][1], bh1, acc[rt][ct]);
      acc[rt][ct] = MFMA16(afh[rt][0], bl0, acc[rt][ct]);
      acc[rt][ct] = MFMA16(afh[rt][1], bl1, acc[rt][ct]);
    }
  }

  // ---- epilogue ----
  bool isRU = (col0 < 1536);
#pragma unroll
  for (int ct = 0; ct < 4; ++ct) {
    int col = col0 + wc0 + ct * 16 + c;
    float bs = bias[col];
    if (isRU) {
#pragma unroll
      for (int rt = 0; rt < 4; ++rt) {
        int lr0 = rt * 16 + g * 4;
#pragma unroll
        for (int r = 0; r < 4; ++r) {
          int n = n0base + lr0 + r;
          if (n <= 960)
            RU[(size_t)(m0 + lr0 + r) * 1536 + col] = f2bf(acc[rt][ct][r] + bs);
        }
      }
    } else {
      int hd = col - 1536;
      int hh = hd >> 6, d = hd & 63;
      size_t vrow = ((size_t)(hh * 8 + b) * 64 + d) * 968;
#pragma unroll
      for (int rt = 0; rt < 4; ++rt) {
        int n0 = n0base + rt * 16 + g * 4;
        if (n0 + 3 <= 960) {
          ushort4 o;
          o.x = f2bf(acc[rt][ct][0] + bs);
          o.y = f2bf(acc[rt][ct][1] + bs);
          o.z = f2bf(acc[rt][ct][2] + bs);
          o.w = f2bf(acc[rt][ct][3] + bs);
          *(ushort4*)&Vt[vrow + n0] = o;
        } else {
#pragma unroll
          for (int r = 0; r < 4; ++r) {
            int n = n0 + r;
            if (n <= 960) Vt[vrow + n] = f2bf(acc[rt][ct][r] + bs);
          }
        }
      }
    }
  }
}

// ---------------------------------------------------------------------------
// Fused heterogeneous kernel: attention (every 11th block) + fold_wp (rest).
// Attention: QB=128, double-buffered K/V, one barrier/tile, unmasked exp for
// kt<15 (keys <= 959 always valid).
// ---------------------------------------------------------------------------
__global__ __launch_bounds__(512) void attn_wp_k(
    const unsigned short* __restrict__ RU,
    const unsigned short* __restrict__ Vt,
    float* __restrict__ O,
    const float* __restrict__ Wp1, const float* __restrict__ Wp2,
    float* __restrict__ wfold)
{
  __shared__ unsigned short sh[24576];       // 48 KB
  int bid = blockIdx.x;
  int tid = threadIdx.x;

  if ((bid % 11) != 0) {
    float* w2 = (float*)sh;
    for (int i = tid; i < 1536; i += 512) w2[i] = Wp2[i];
    __syncthreads();
    int fid = bid - bid / 11 - 1;
    int wv = tid >> 6, lane = tid & 63;
    for (int m8 = fid; m8 < 7688; m8 += 7680) {
      int m = m8 * 8 + wv;
      const float* row = Wp1 + (size_t)m * 1536;
      float s = 0.f;
#pragma unroll
      for (int k = 0; k < 6; ++k) {
        float4 a  = *(const float4*)(row + k * 256 + lane * 4);
        float4 ww = *(const float4*)&w2[k * 256 + lane * 4];
        s += a.x * ww.x + a.y * ww.y + a.z * ww.z + a.w * ww.w;
      }
#pragma unroll
      for (int off2 = 32; off2 >= 1; off2 >>= 1) s += __shfl_xor(s, off2, 64);
      if (lane == 0) wfold[m] = s;
    }
    return;
  }

  const int NS = 961, RS = 1536, VROW = 968;
  int aid = bid / 11;
  int qb = aid & 7, hb = aid >> 3;
  int h = hb >> 3, b = hb & 7;
  int n0 = qb * 128;
  int w = tid >> 6, lane = tid & 63;
  int g = lane >> 4, c = lane & 15;
  const unsigned short* rubase = RU + (size_t)b * NS * RS;
  int roff = h * 64, uoff = 768 + h * 64;
  const unsigned short* vtbase = Vt + (size_t)hb * 64 * VROW;
  unsigned short* Kbuf[2] = {sh, sh + 4096};
  unsigned short* Vbuf[2] = {sh + 8192, sh + 12288};
  unsigned short* pw = sh + 16384 + w * 1024;

  int qrow = n0 + w * 16 + c;
  if (qrow > 960) qrow = 960;
  bf16x8 qf0 = *(const bf16x8*)(rubase + (size_t)qrow * RS + roff + g * 8);
  bf16x8 qf1 = *(const bf16x8*)(rubase + (size_t)qrow * RS + roff + 32 + g * 8);

  int srow = tid >> 3, ss = tid & 7;
  int sel = srow * 64 + 8 * (ss ^ (srow & 7));
  const unsigned short* ksrc = rubase + uoff + ss * 8;
  const unsigned short* vsrc = vtbase + (size_t)srow * VROW + ss * 8;

  {
    int4 kv = *(const int4*)(ksrc + (size_t)srow * RS);
    int4 vv = *(const int4*)(vsrc);
    *(int4*)&Kbuf[0][sel] = kv;
    *(int4*)&Vbuf[0][sel] = vv;
  }
  __syncthreads();

  f32x4 zero4 = {0.f, 0.f, 0.f, 0.f};
  f32x4 oacc[4] = {zero4, zero4, zero4, zero4};
  float rowsum[4] = {0.f, 0.f, 0.f, 0.f};

  unsigned short* Kc = Kbuf[0];
  unsigned short* Vc = Vbuf[0];
  unsigned short* Kn = Kbuf[1];
  unsigned short* Vn = Vbuf[1];

  for (int kt = 0; kt < 16; ++kt) {
    int4 pk, pv;
    bool pre = (kt < 15);
    if (pre) {
      int keyg = (kt + 1) * 64 + srow;
      int kcl = keyg > 960 ? 960 : keyg;
      pk = *(const int4*)(ksrc + (size_t)kcl * RS);
      pv = *(const int4*)(vsrc + (kt + 1) * 64);
    }

    f32x4 sa[4] = {zero4, zero4, zero4, zero4};
    __builtin_amdgcn_s_setprio(1);
#pragma unroll
    for (int ct = 0; ct < 4; ++ct) {
      int key = c * 4 + ct;
      int sw = (key & 7) * 8;
      bf16x8 k0 = *(const bf16x8*)&Kc[key * 64 + ((g * 8) ^ sw)];
      bf16x8 k1 = *(const bf16x8*)&Kc[key * 64 + ((32 + g * 8) ^ sw)];
      sa[ct] = MFMA16(qf0, k0, sa[ct]);
      sa[ct] = MFMA16(qf1, k1, sa[ct]);
    }
    __builtin_amdgcn_s_setprio(0);

    if (kt < 15) {
      // keys kt*64 + c*4+ct <= 959: always valid, no masking
#pragma unroll
      for (int r = 0; r < 4; ++r) {
        unsigned short pb[4];
#pragma unroll
        for (int ct = 0; ct < 4; ++ct) {
          unsigned short p16 = f2bf(__expf(sa[ct][r]));
          pb[ct] = p16;
          rowsum[r] += bf2f(p16);
        }
        int q = g * 4 + r;
        int e0 = (c * 4) ^ ((q & 7) * 8);
        *(unsigned int*)&pw[q * 64 + e0] =
            (unsigned int)pb[0] | ((unsigned int)pb[1] << 16);
        *(unsigned int*)&pw[q * 64 + e0 + 2] =
            (unsigned int)pb[2] | ((unsigned int)pb[3] << 16);
      }
    } else {
#pragma unroll
      for (int r = 0; r < 4; ++r) {
        unsigned short pb[4];
#pragma unroll
        for (int ct = 0; ct < 4; ++ct) {
          int keyg = kt * 64 + c * 4 + ct;
          unsigned short p16 = 0;
          if (keyg <= 960) p16 = f2bf(__expf(sa[ct][r]));
          pb[ct] = p16;
          rowsum[r] += bf2f(p16);
        }
        int q = g * 4 + r;
        int e0 = (c * 4) ^ ((q & 7) * 8);
        *(unsigned int*)&pw[q * 64 + e0] =
            (unsigned int)pb[0] | ((unsigned int)pb[1] << 16);
        *(unsigned int*)&pw[q * 64 + e0 + 2] =
            (unsigned int)pb[2] | ((unsigned int)pb[3] << 16);
      }
    }

    if (pre) {
      *(int4*)&Kn[sel] = pk;
      *(int4*)&Vn[sel] = pv;
    }

    __builtin_amdgcn_s_setprio(1);
#pragma unroll
    for (int kk = 0; kk < 2; ++kk) {
      bf16x8 pa = *(const bf16x8*)&pw[c * 64 + ((kk * 32 + g * 8) ^ ((c & 7) * 8))];
#pragma unroll
      for (int dt = 0; dt < 4; ++dt) {
        int d = dt * 16 + c;
        bf16x8 vf = *(const bf16x8*)&Vc[d * 64 + ((kk * 32 + g * 8) ^ ((d & 7) * 8))];
        oacc[dt] = MFMA16(pa, vf, oacc[dt]);
      }
    }
    __builtin_amdgcn_s_setprio(0);

    __syncthreads();
    unsigned short* t;
    t = Kc; Kc = Kn; Kn = t;
    t = Vc; Vc = Vn; Vn = t;
  }

#pragma unroll
  for (int r = 0; r < 4; ++r) {
    float s = rowsum[r];
    s += __shfl_xor(s, 1, 64);
    s += __shfl_xor(s, 2, 64);
    s += __shfl_xor(s, 4, 64);
    s += __shfl_xor(s, 8, 64);
    rowsum[r] = 1.f / s;
  }
  int nbase = n0 + w * 16 + g * 4;
  float* ob = O + (size_t)hb * 61504;
#pragma unroll
  for (int r = 0; r < 4; ++r) {
    int n = nbase + r;
    if (n > 960) continue;
#pragma unroll
    for (int dt = 0; dt < 4; ++dt)
      ob[(size_t)n * 64 + dt * 16 + c] = oacc[dt][r] * rowsum[r];
  }
}

// ---------------------------------------------------------------------------
// out[b*12+h] = O[hb,:] . wfold + bp1 . Wp2 + bp2
// ---------------------------------------------------------------------------
__global__ __launch_bounds__(TPB) void final_k(
    const float* __restrict__ O, const float* __restrict__ wfold,
    const float* __restrict__ bp1, const float* __restrict__ Wp2,
    const float* __restrict__ bp2, float* __restrict__ out)
{
  int hb = blockIdx.x;
  int h = hb >> 3, b = hb & 7;
  int tid = threadIdx.x;
  const float* orow = O + (size_t)hb * 61504;
  float s = 0.f;
  for (int i4 = tid; i4 < 15376; i4 += 256) {
    float4 a = *(const float4*)(orow + (size_t)i4 * 4);
    float4 w = *(const float4*)(wfold + (size_t)i4 * 4);
    s += a.x * w.x + a.y * w.y + a.z * w.z + a.w * w.w;
  }
  for (int p = tid; p < 1536; p += 256) s += bp1[p] * Wp2[p];
#pragma unroll
  for (int off = 32; off >= 1; off >>= 1) s += __shfl_xor(s, off, 64);
  __shared__ float red[4];
  if ((tid & 63) == 0) red[tid >> 6] = s;
  __syncthreads();
  if (tid == 0) out[b * 12 + h] = red[0] + red[1] + red[2] + red[3] + bp2[0];
}

// ---------------------------------------------------------------------------
extern "C" void kernel_launch(void* const* d_in, const int* in_sizes, int n_in,
                              void* d_out, int out_size, void* d_ws, size_t ws_size,
                              hipStream_t stream)
{
  const float* x    = (const float*)d_in[0];
  const float* W1   = (const float*)d_in[1];
  const float* b1   = (const float*)d_in[2];
  const float* W2   = (const float*)d_in[3];
  const float* b2   = (const float*)d_in[4];
  const float* W3   = (const float*)d_in[5];
  const float* b3   = (const float*)d_in[6];
  const float* W4   = (const float*)d_in[7];
  const float* b4   = (const float*)d_in[8];
  const float* Wruv = (const float*)d_in[9];
  const float* bruv = (const float*)d_in[10];
  const float* Wp1  = (const float*)d_in[11];
  const float* bp1  = (const float*)d_in[12];
  const float* Wp2  = (const float*)d_in[13];
  const float* bp2  = (const float*)d_in[14];
  float* out = (float*)d_out;

  char* base = (char*)d_ws;
  size_t off = 0;
  auto alloc = [&](size_t bytes) -> void* {
    void* p = base + off;
    off = (off + bytes + 255) & ~(size_t)255;
    return p;
  };
  unsigned short* RU  = (unsigned short*)alloc((size_t)7688 * 1536 * 2);          // 23.6 MB
  unsigned short* Vt  = (unsigned short*)alloc((size_t)96 * 64 * 968 * 2 + 1024); // 11.9 MB
  float* Ob    = (float*)alloc((size_t)96 * 61504 * 4);                           // 23.6 MB
  float* aug1  = (float*)alloc(51 * 200 * 4);
  float* aug2  = (float*)alloc(51 * 200 * 4);
  float* aug3  = (float*)alloc(51 * 768 * 4);
  unsigned short* WfTh = (unsigned short*)alloc((size_t)2304 * 64 * 2);
  unsigned short* WfTl = (unsigned short*)alloc((size_t)2304 * 64 * 2);
  unsigned short* xh   = (unsigned short*)alloc((size_t)(7688 + 64) * 64 * 2);    // ~1 MB
  unsigned short* xl   = (unsigned short*)alloc((size_t)(7688 + 64) * 64 * 2);
  float* bfv   = (float*)alloc(2304 * 4);
  float* wfold = (float*)alloc(61504 * 4);
  if (off > ws_size) return;

  dim3 tb(TPB);

  // ---- fold MLP chain (stages 1-3, fp32 augmented) ----
  gemm_fold_k<<<dim3(4),  tb, 0, stream>>>(W1,   b1,            W2, b2, aug1, 200, 200);
  gemm_fold_k<<<dim3(4),  tb, 0, stream>>>(aug1, aug1 + 50*200, W3, b3, aug2, 200, 200);
  gemm_fold_k<<<dim3(12), tb, 0, stream>>>(aug2, aug2 + 50*200, W4, b4, aug3, 200, 768);

  // ---- stage4 (-> WfTh/WfTl/bfv) fused with x split-prep (-> xh/xl) ----
  fold4_xprep_k<<<dim3(157), tb, 0, stream>>>(aug3, Wruv, bruv, WfTh, WfTl, bfv, x, xh, xl);

  // ---- ruv = x @ Wf + bf (split-bf16 MFMA, no-LDS v3) -> RU + Vt ----
  gemm_ruv_mfma_k<<<dim3(9, 128), tb, 0, stream>>>(xh, xl, WfTh, WfTl, bfv, RU, Vt);

  // ---- fused: MFMA flash attention (768 blocks) + Wp1@Wp2 fold (7680) ----
  attn_wp_k<<<dim3(8448), dim3(512), 0, stream>>>(RU, Vt, Ob, Wp1, Wp2, wfold);

  // ---- final scalar per (h,b) ----
  final_k<<<dim3(96), tb, 0, stream>>>(Ob, wfold, bp1, Wp2, bp2, out);
}

// Round 13
// 401.532 us; speedup vs baseline: 1.2424x; 1.0143x over previous
//
#include <hip/hip_runtime.h>
#include <hip/hip_bf16.h>

#define TPB 256

typedef __attribute__((ext_vector_type(8))) short bf16x8;
typedef __attribute__((ext_vector_type(4))) float f32x4;

static __device__ __forceinline__ unsigned short f2bf(float f) {
  union { float f; unsigned int u; } x; x.f = f;
  unsigned int r = x.u + 0x7FFF + ((x.u >> 16) & 1);   // RNE
  return (unsigned short)(r >> 16);
}
static __device__ __forceinline__ float bf2f(unsigned short h) {
  union { unsigned int u; float f; } x; x.u = ((unsigned int)h) << 16;
  return x.f;
}

#define MFMA16(a, b, c) __builtin_amdgcn_mfma_f32_16x16x32_bf16(a, b, c, 0, 0, 0)

// ---------------------------------------------------------------------------
// Augmented fold GEMM, fp32 out (stages 1-3). Unchanged.
// ---------------------------------------------------------------------------
__global__ __launch_bounds__(TPB) void gemm_fold_k(
    const float* __restrict__ A, const float* __restrict__ lastrow,
    const float* __restrict__ W, const float* __restrict__ bias,
    float* __restrict__ C, int K, int Nc)
{
  __shared__ float As[16][68];
  __shared__ float Ws[16][68];
  int tid = threadIdx.x;
  int col0 = blockIdx.x * 64;
  int ty = tid >> 4, tx = tid & 15;
  float acc[4][4] = {};
  for (int k0 = 0; k0 < K; k0 += 16) {
#pragma unroll
    for (int i = 0; i < 4; ++i) {
      int idx = tid + i * 256;
      int r = idx >> 4, kk = idx & 15;
      int gk = k0 + kk;
      float v = 0.f;
      if (gk < K) {
        if (r < 50) v = A[(size_t)r * K + gk];
        else if (r == 50) v = lastrow[gk];
      }
      As[kk][r] = v;
    }
#pragma unroll
    for (int i = 0; i < 4; ++i) {
      int idx = tid + i * 256;
      int c = idx & 63, kk = idx >> 6;
      int gc = col0 + c, gk = k0 + kk;
      float v = 0.f;
      if (gk < K && gc < Nc) v = W[(size_t)gk * Nc + gc];
      Ws[kk][c] = v;
    }
    __syncthreads();
#pragma unroll
    for (int kk = 0; kk < 16; ++kk) {
      float4 a4 = *(const float4*)&As[kk][ty * 4];
      float4 b4 = *(const float4*)&Ws[kk][tx * 4];
      float av[4] = {a4.x, a4.y, a4.z, a4.w};
      float bv[4] = {b4.x, b4.y, b4.z, b4.w};
#pragma unroll
      for (int i = 0; i < 4; ++i)
#pragma unroll
        for (int j = 0; j < 4; ++j)
          acc[i][j] = fmaf(av[i], bv[j], acc[i][j]);
    }
    __syncthreads();
  }
#pragma unroll
  for (int i = 0; i < 4; ++i) {
    int gr = ty * 4 + i;
    if (gr >= 51) continue;
#pragma unroll
    for (int j = 0; j < 4; ++j) {
      int gc = col0 + tx * 4 + j;
      if (gc >= Nc) continue;
      float v = acc[i][j];
      if (gr == 50) v += bias[gc];
      C[(size_t)gr * Nc + gc] = v;
    }
  }
}

// ---------------------------------------------------------------------------
// Fused stage4 + x-prep kernel. Unchanged.
// ---------------------------------------------------------------------------
__global__ __launch_bounds__(TPB) void fold4_xprep_k(
    const float* __restrict__ aug3,   // [51][768]
    const float* __restrict__ Wruv,   // [768][2304]
    const float* __restrict__ bruv,   // [2304]
    unsigned short* __restrict__ WfTh, unsigned short* __restrict__ WfTl,
    float* __restrict__ bfv,
    const float* __restrict__ x,      // [7688][50]
    unsigned short* __restrict__ xh, unsigned short* __restrict__ xl)
{
  __shared__ float As[16][68];
  __shared__ float Ws[16][68];
  int bid = blockIdx.x;
  int tid = threadIdx.x;

  if (bid >= 36) {
    int row0 = (bid - 36) * 64;
#pragma unroll
    for (int i = 0; i < 16; ++i) {
      int idx = tid + i * 256;
      int row = row0 + (idx >> 6), cc = idx & 63;
      if (row >= 7688) continue;
      float v = (cc < 50) ? x[(size_t)row * 50 + cc] : 0.f;
      unsigned short hi = f2bf(v);
      xh[(size_t)row * 64 + cc] = hi;
      xl[(size_t)row * 64 + cc] = f2bf(v - bf2f(hi));
    }
    return;
  }

  const int K = 768, Nc = 2304;
  const float* lastrow = aug3 + (size_t)50 * 768;
  int col0 = bid * 64;
  int ty = tid >> 4, tx = tid & 15;
  float acc[4][4] = {};
  for (int k0 = 0; k0 < K; k0 += 16) {
#pragma unroll
    for (int i = 0; i < 4; ++i) {
      int idx = tid + i * 256;
      int r = idx >> 4, kk = idx & 15;
      int gk = k0 + kk;
      float v = 0.f;
      if (r < 50) v = aug3[(size_t)r * K + gk];
      else if (r == 50) v = lastrow[gk];
      As[kk][r] = v;
    }
#pragma unroll
    for (int i = 0; i < 4; ++i) {
      int idx = tid + i * 256;
      int c = idx & 63, kk = idx >> 6;
      Ws[kk][c] = Wruv[(size_t)(k0 + kk) * Nc + col0 + c];
    }
    __syncthreads();
#pragma unroll
    for (int kk = 0; kk < 16; ++kk) {
      float4 a4 = *(const float4*)&As[kk][ty * 4];
      float4 b4 = *(const float4*)&Ws[kk][tx * 4];
      float av[4] = {a4.x, a4.y, a4.z, a4.w};
      float bv[4] = {b4.x, b4.y, b4.z, b4.w};
#pragma unroll
      for (int i = 0; i < 4; ++i)
#pragma unroll
        for (int j = 0; j < 4; ++j)
          acc[i][j] = fmaf(av[i], bv[j], acc[i][j]);
    }
    __syncthreads();
  }
#pragma unroll
  for (int i = 0; i < 4; ++i) {
    int gr = ty * 4 + i;
    if (gr >= 51) continue;
#pragma unroll
    for (int j = 0; j < 4; ++j) {
      int gc = col0 + tx * 4 + j;
      float v = acc[i][j];
      if (gr == 50) {
        bfv[gc] = v + bruv[gc];
      } else {
        unsigned short hi = f2bf(v);
        size_t el = (size_t)gc * 64 + gr;       // LINEAR layout
        WfTh[el] = hi;
        WfTl[el] = f2bf(v - bf2f(hi));
      }
    }
  }
}

// ---------------------------------------------------------------------------
// Split-precision MFMA ruv GEMM v3 — no LDS, no barriers. Unchanged.
// ---------------------------------------------------------------------------
__global__ __launch_bounds__(TPB) void gemm_ruv_mfma_k(
    const unsigned short* __restrict__ xh,    // [7688+64][64] bf16
    const unsigned short* __restrict__ xl,
    const unsigned short* __restrict__ WfTh,  // [2304][64] bf16 linear
    const unsigned short* __restrict__ WfTl,
    const float* __restrict__ bias,           // [2304] fp32
    unsigned short* __restrict__ RU,          // [7688][1536]
    unsigned short* __restrict__ Vt)          // [hb][64][968], hb=h*8+b
{
  int tid = threadIdx.x, w = tid >> 6, lane = tid & 63;
  int g = lane >> 4, c = lane & 15;
  int by = blockIdx.y;
  int b = by >> 4, nb = by & 15;
  int m0 = b * 961 + nb * 64;
  int n0base = nb * 64;
  int col0 = blockIdx.x * 256;
  int wc0 = w * 64;

  bf16x8 afh[4][2], afl[4][2];
#pragma unroll
  for (int rt = 0; rt < 4; ++rt) {
    size_t rowb = (size_t)(m0 + rt * 16 + c) * 64;
#pragma unroll
    for (int kk = 0; kk < 2; ++kk) {
      afh[rt][kk] = *(const bf16x8*)&xh[rowb + kk * 32 + g * 8];
      afl[rt][kk] = *(const bf16x8*)&xl[rowb + kk * 32 + g * 8];
    }
  }

  f32x4 zero4 = {0.f, 0.f, 0.f, 0.f};
  f32x4 acc[4][4] = {{zero4, zero4, zero4, zero4}, {zero4, zero4, zero4, zero4},
                     {zero4, zero4, zero4, zero4}, {zero4, zero4, zero4, zero4}};

#pragma unroll
  for (int ct = 0; ct < 4; ++ct) {
    size_t bcolb = (size_t)(col0 + wc0 + ct * 16 + c) * 64;
    bf16x8 bh0 = *(const bf16x8*)&WfTh[bcolb + g * 8];
    bf16x8 bh1 = *(const bf16x8*)&WfTh[bcolb + 32 + g * 8];
    bf16x8 bl0 = *(const bf16x8*)&WfTl[bcolb + g * 8];
    bf16x8 bl1 = *(const bf16x8*)&WfTl[bcolb + 32 + g * 8];
#pragma unroll
    for (int rt = 0; rt < 4; ++rt) {
      acc[rt][ct] = MFMA16(afh[rt][0], bh0, acc[rt][ct]);
      acc[rt][ct] = MFMA16(afh[rt][1], bh1, acc[rt][ct]);
      acc[rt][ct] = MFMA16(afl[rt][0], bh0, acc[rt][ct]);
      acc[rt][ct] = MFMA16(afl[rt][1], bh1, acc[rt][ct]);
      acc[rt][ct] = MFMA16(afh[rt][0], bl0, acc[rt][ct]);
      acc[rt][ct] = MFMA16(afh[rt][1], bl1, acc[rt][ct]);
    }
  }

  bool isRU = (col0 < 1536);
#pragma unroll
  for (int ct = 0; ct < 4; ++ct) {
    int col = col0 + wc0 + ct * 16 + c;
    float bs = bias[col];
    if (isRU) {
#pragma unroll
      for (int rt = 0; rt < 4; ++rt) {
        int lr0 = rt * 16 + g * 4;
#pragma unroll
        for (int r = 0; r < 4; ++r) {
          int n = n0base + lr0 + r;
          if (n <= 960)
            RU[(size_t)(m0 + lr0 + r) * 1536 + col] = f2bf(acc[rt][ct][r] + bs);
        }
      }
    } else {
      int hd = col - 1536;
      int hh = hd >> 6, d = hd & 63;
      size_t vrow = ((size_t)(hh * 8 + b) * 64 + d) * 968;
#pragma unroll
      for (int rt = 0; rt < 4; ++rt) {
        int n0 = n0base + rt * 16 + g * 4;
        if (n0 + 3 <= 960) {
          ushort4 o;
          o.x = f2bf(acc[rt][ct][0] + bs);
          o.y = f2bf(acc[rt][ct][1] + bs);
          o.z = f2bf(acc[rt][ct][2] + bs);
          o.w = f2bf(acc[rt][ct][3] + bs);
          *(ushort4*)&Vt[vrow + n0] = o;
        } else {
#pragma unroll
          for (int r = 0; r < 4; ++r) {
            int n = n0 + r;
            if (n <= 960) Vt[vrow + n] = f2bf(acc[rt][ct][r] + bs);
          }
        }
      }
    }
  }
}

// ---------------------------------------------------------------------------
// Fused heterogeneous kernel: attention (every 11th block) + fold_wp (rest).
// This round: packing reverted to f2bf (cvt_pk suspect from r12); rowsum
// via ones-MFMA KEPT (layout-insensitive, removes rowsum VALU + shuffles).
// ---------------------------------------------------------------------------
__global__ __launch_bounds__(512) void attn_wp_k(
    const unsigned short* __restrict__ RU,
    const unsigned short* __restrict__ Vt,
    float* __restrict__ O,
    const float* __restrict__ Wp1, const float* __restrict__ Wp2,
    float* __restrict__ wfold)
{
  __shared__ unsigned short sh[24576];       // 48 KB
  int bid = blockIdx.x;
  int tid = threadIdx.x;

  if ((bid % 11) != 0) {
    float* w2 = (float*)sh;
    for (int i = tid; i < 1536; i += 512) w2[i] = Wp2[i];
    __syncthreads();
    int fid = bid - bid / 11 - 1;
    int wv = tid >> 6, lane = tid & 63;
    for (int m8 = fid; m8 < 7688; m8 += 7680) {
      int m = m8 * 8 + wv;
      const float* row = Wp1 + (size_t)m * 1536;
      float s = 0.f;
#pragma unroll
      for (int k = 0; k < 6; ++k) {
        float4 a  = *(const float4*)(row + k * 256 + lane * 4);
        float4 ww = *(const float4*)&w2[k * 256 + lane * 4];
        s += a.x * ww.x + a.y * ww.y + a.z * ww.z + a.w * ww.w;
      }
#pragma unroll
      for (int off2 = 32; off2 >= 1; off2 >>= 1) s += __shfl_xor(s, off2, 64);
      if (lane == 0) wfold[m] = s;
    }
    return;
  }

  const int NS = 961, RS = 1536, VROW = 968;
  int aid = bid / 11;
  int qb = aid & 7, hb = aid >> 3;
  int h = hb >> 3, b = hb & 7;
  int n0 = qb * 128;
  int w = tid >> 6, lane = tid & 63;
  int g = lane >> 4, c = lane & 15;
  const unsigned short* rubase = RU + (size_t)b * NS * RS;
  int roff = h * 64, uoff = 768 + h * 64;
  const unsigned short* vtbase = Vt + (size_t)hb * 64 * VROW;
  unsigned short* Kbuf[2] = {sh, sh + 4096};
  unsigned short* Vbuf[2] = {sh + 8192, sh + 12288};
  unsigned short* pw = sh + 16384 + w * 1024;

  int qrow = n0 + w * 16 + c;
  if (qrow > 960) qrow = 960;
  bf16x8 qf0 = *(const bf16x8*)(rubase + (size_t)qrow * RS + roff + g * 8);
  bf16x8 qf1 = *(const bf16x8*)(rubase + (size_t)qrow * RS + roff + 32 + g * 8);

  bf16x8 ones;
#pragma unroll
  for (int i = 0; i < 8; ++i) ones[i] = (short)0x3F80;  // bf16 1.0

  int srow = tid >> 3, ss = tid & 7;
  int sel = srow * 64 + 8 * (ss ^ (srow & 7));
  const unsigned short* ksrc = rubase + uoff + ss * 8;
  const unsigned short* vsrc = vtbase + (size_t)srow * VROW + ss * 8;

  {
    int4 kv = *(const int4*)(ksrc + (size_t)srow * RS);
    int4 vv = *(const int4*)(vsrc);
    *(int4*)&Kbuf[0][sel] = kv;
    *(int4*)&Vbuf[0][sel] = vv;
  }
  __syncthreads();

  f32x4 zero4 = {0.f, 0.f, 0.f, 0.f};
  f32x4 oacc[4] = {zero4, zero4, zero4, zero4};
  f32x4 rowacc = zero4;                      // denominator via ones-MFMA

  unsigned short* Kc = Kbuf[0];
  unsigned short* Vc = Vbuf[0];
  unsigned short* Kn = Kbuf[1];
  unsigned short* Vn = Vbuf[1];

  for (int kt = 0; kt < 16; ++kt) {
    int4 pk, pv;
    bool pre = (kt < 15);
    if (pre) {
      int keyg = (kt + 1) * 64 + srow;
      int kcl = keyg > 960 ? 960 : keyg;
      pk = *(const int4*)(ksrc + (size_t)kcl * RS);
      pv = *(const int4*)(vsrc + (kt + 1) * 64);
    }

    f32x4 sa[4] = {zero4, zero4, zero4, zero4};
    __builtin_amdgcn_s_setprio(1);
#pragma unroll
    for (int ct = 0; ct < 4; ++ct) {
      int key = c * 4 + ct;
      int sw = (key & 7) * 8;
      bf16x8 k0 = *(const bf16x8*)&Kc[key * 64 + ((g * 8) ^ sw)];
      bf16x8 k1 = *(const bf16x8*)&Kc[key * 64 + ((32 + g * 8) ^ sw)];
      sa[ct] = MFMA16(qf0, k0, sa[ct]);
      sa[ct] = MFMA16(qf1, k1, sa[ct]);
    }
    __builtin_amdgcn_s_setprio(0);

    if (kt < 15) {
      // keys always valid: exp + f2bf pack (proven path), b32 pair stores
#pragma unroll
      for (int r = 0; r < 4; ++r) {
        unsigned short pb[4];
#pragma unroll
        for (int ct = 0; ct < 4; ++ct)
          pb[ct] = f2bf(__expf(sa[ct][r]));
        int q = g * 4 + r;
        int e0 = (c * 4) ^ ((q & 7) * 8);
        *(unsigned int*)&pw[q * 64 + e0] =
            (unsigned int)pb[0] | ((unsigned int)pb[1] << 16);
        *(unsigned int*)&pw[q * 64 + e0 + 2] =
            (unsigned int)pb[2] | ((unsigned int)pb[3] << 16);
      }
    } else {
#pragma unroll
      for (int r = 0; r < 4; ++r) {
        unsigned short pb[4];
#pragma unroll
        for (int ct = 0; ct < 4; ++ct) {
          int keyg = kt * 64 + c * 4 + ct;
          pb[ct] = (keyg <= 960) ? f2bf(__expf(sa[ct][r])) : (unsigned short)0;
        }
        int q = g * 4 + r;
        int e0 = (c * 4) ^ ((q & 7) * 8);
        *(unsigned int*)&pw[q * 64 + e0] =
            (unsigned int)pb[0] | ((unsigned int)pb[1] << 16);
        *(unsigned int*)&pw[q * 64 + e0 + 2] =
            (unsigned int)pb[2] | ((unsigned int)pb[3] << 16);
      }
    }

    if (pre) {
      *(int4*)&Kn[sel] = pk;
      *(int4*)&Vn[sel] = pv;
    }

    __builtin_amdgcn_s_setprio(1);
#pragma unroll
    for (int kk = 0; kk < 2; ++kk) {
      bf16x8 pa = *(const bf16x8*)&pw[c * 64 + ((kk * 32 + g * 8) ^ ((c & 7) * 8))];
      rowacc = MFMA16(pa, ones, rowacc);     // denominator, consistent with PV
#pragma unroll
      for (int dt = 0; dt < 4; ++dt) {
        int d = dt * 16 + c;
        bf16x8 vf = *(const bf16x8*)&Vc[d * 64 + ((kk * 32 + g * 8) ^ ((d & 7) * 8))];
        oacc[dt] = MFMA16(pa, vf, oacc[dt]);
      }
    }
    __builtin_amdgcn_s_setprio(0);

    __syncthreads();
    unsigned short* t;
    t = Kc; Kc = Kn; Kn = t;
    t = Vc; Vc = Vn; Vn = t;
  }

  // ---- finalize: rowacc already holds full row sums (no shuffles) ----
  int nbase = n0 + w * 16 + g * 4;
  float* ob = O + (size_t)hb * 61504;
#pragma unroll
  for (int r = 0; r < 4; ++r) {
    int n = nbase + r;
    if (n > 960) continue;
    float inv = 1.f / rowacc[r];
#pragma unroll
    for (int dt = 0; dt < 4; ++dt)
      ob[(size_t)n * 64 + dt * 16 + c] = oacc[dt][r] * inv;
  }
}

// ---------------------------------------------------------------------------
// out[b*12+h] = O[hb,:] . wfold + bp1 . Wp2 + bp2. Unchanged.
// ---------------------------------------------------------------------------
__global__ __launch_bounds__(TPB) void final_k(
    const float* __restrict__ O, const float* __restrict__ wfold,
    const float* __restrict__ bp1, const float* __restrict__ Wp2,
    const float* __restrict__ bp2, float* __restrict__ out)
{
  int hb = blockIdx.x;
  int h = hb >> 3, b = hb & 7;
  int tid = threadIdx.x;
  const float* orow = O + (size_t)hb * 61504;
  float s = 0.f;
  for (int i4 = tid; i4 < 15376; i4 += 256) {
    float4 a = *(const float4*)(orow + (size_t)i4 * 4);
    float4 w = *(const float4*)(wfold + (size_t)i4 * 4);
    s += a.x * w.x + a.y * w.y + a.z * w.z + a.w * w.w;
  }
  for (int p = tid; p < 1536; p += 256) s += bp1[p] * Wp2[p];
#pragma unroll
  for (int off = 32; off >= 1; off >>= 1) s += __shfl_xor(s, off, 64);
  __shared__ float red[4];
  if ((tid & 63) == 0) red[tid >> 6] = s;
  __syncthreads();
  if (tid == 0) out[b * 12 + h] = red[0] + red[1] + red[2] + red[3] + bp2[0];
}

// ---------------------------------------------------------------------------
extern "C" void kernel_launch(void* const* d_in, const int* in_sizes, int n_in,
                              void* d_out, int out_size, void* d_ws, size_t ws_size,
                              hipStream_t stream)
{
  const float* x    = (const float*)d_in[0];
  const float* W1   = (const float*)d_in[1];
  const float* b1   = (const float*)d_in[2];
  const float* W2   = (const float*)d_in[3];
  const float* b2   = (const float*)d_in[4];
  const float* W3   = (const float*)d_in[5];
  const float* b3   = (const float*)d_in[6];
  const float* W4   = (const float*)d_in[7];
  const float* b4   = (const float*)d_in[8];
  const float* Wruv = (const float*)d_in[9];
  const float* bruv = (const float*)d_in[10];
  const float* Wp1  = (const float*)d_in[11];
  const float* bp1  = (const float*)d_in[12];
  const float* Wp2  = (const float*)d_in[13];
  const float* bp2  = (const float*)d_in[14];
  float* out = (float*)d_out;

  char* base = (char*)d_ws;
  size_t off = 0;
  auto alloc = [&](size_t bytes) -> void* {
    void* p = base + off;
    off = (off + bytes + 255) & ~(size_t)255;
    return p;
  };
  unsigned short* RU  = (unsigned short*)alloc((size_t)7688 * 1536 * 2);          // 23.6 MB
  unsigned short* Vt  = (unsigned short*)alloc((size_t)96 * 64 * 968 * 2 + 1024); // 11.9 MB
  float* Ob    = (float*)alloc((size_t)96 * 61504 * 4);                           // 23.6 MB
  float* aug1  = (float*)alloc(51 * 200 * 4);
  float* aug2  = (float*)alloc(51 * 200 * 4);
  float* aug3  = (float*)alloc(51 * 768 * 4);
  unsigned short* WfTh = (unsigned short*)alloc((size_t)2304 * 64 * 2);
  unsigned short* WfTl = (unsigned short*)alloc((size_t)2304 * 64 * 2);
  unsigned short* xh   = (unsigned short*)alloc((size_t)(7688 + 64) * 64 * 2);    // ~1 MB
  unsigned short* xl   = (unsigned short*)alloc((size_t)(7688 + 64) * 64 * 2);
  float* bfv   = (float*)alloc(2304 * 4);
  float* wfold = (float*)alloc(61504 * 4);
  if (off > ws_size) return;

  dim3 tb(TPB);

  // ---- fold MLP chain (stages 1-3, fp32 augmented) ----
  gemm_fold_k<<<dim3(4),  tb, 0, stream>>>(W1,   b1,            W2, b2, aug1, 200, 200);
  gemm_fold_k<<<dim3(4),  tb, 0, stream>>>(aug1, aug1 + 50*200, W3, b3, aug2, 200, 200);
  gemm_fold_k<<<dim3(12), tb, 0, stream>>>(aug2, aug2 + 50*200, W4, b4, aug3, 200, 768);

  // ---- stage4 (-> WfTh/WfTl/bfv) fused with x split-prep (-> xh/xl) ----
  fold4_xprep_k<<<dim3(157), tb, 0, stream>>>(aug3, Wruv, bruv, WfTh, WfTl, bfv, x, xh, xl);

  // ---- ruv = x @ Wf + bf (split-bf16 MFMA, no-LDS v3) -> RU + Vt ----
  gemm_ruv_mfma_k<<<dim3(9, 128), tb, 0, stream>>>(xh, xl, WfTh, WfTl, bfv, RU, Vt);

  // ---- fused: MFMA flash attention (768 blocks) + Wp1@Wp2 fold (7680) ----
  attn_wp_k<<<dim3(8448), dim3(512), 0, stream>>>(RU, Vt, Ob, Wp1, Wp2, wfold);

  // ---- final scalar per (h,b) ----
  final_k<<<dim3(96), tb, 0, stream>>>(Ob, wfold, bp1, Wp2, bp2, out);
}

// Round 14
// 383.440 us; speedup vs baseline: 1.3011x; 1.0472x over previous
//
#include <hip/hip_runtime.h>
#include <hip/hip_bf16.h>

#define TPB 256

typedef __attribute__((ext_vector_type(8))) short bf16x8;
typedef __attribute__((ext_vector_type(4))) float f32x4;

static __device__ __forceinline__ unsigned short f2bf(float f) {
  union { float f; unsigned int u; } x; x.f = f;
  unsigned int r = x.u + 0x7FFF + ((x.u >> 16) & 1);   // RNE
  return (unsigned short)(r >> 16);
}
static __device__ __forceinline__ float bf2f(unsigned short h) {
  union { unsigned int u; float f; } x; x.u = ((unsigned int)h) << 16;
  return x.f;
}

#define MFMA16(a, b, c) __builtin_amdgcn_mfma_f32_16x16x32_bf16(a, b, c, 0, 0, 0)

// ---------------------------------------------------------------------------
// Augmented fold GEMM, fp32 out (stages 1-3). Unchanged.
// ---------------------------------------------------------------------------
__global__ __launch_bounds__(TPB) void gemm_fold_k(
    const float* __restrict__ A, const float* __restrict__ lastrow,
    const float* __restrict__ W, const float* __restrict__ bias,
    float* __restrict__ C, int K, int Nc)
{
  __shared__ float As[16][68];
  __shared__ float Ws[16][68];
  int tid = threadIdx.x;
  int col0 = blockIdx.x * 64;
  int ty = tid >> 4, tx = tid & 15;
  float acc[4][4] = {};
  for (int k0 = 0; k0 < K; k0 += 16) {
#pragma unroll
    for (int i = 0; i < 4; ++i) {
      int idx = tid + i * 256;
      int r = idx >> 4, kk = idx & 15;
      int gk = k0 + kk;
      float v = 0.f;
      if (gk < K) {
        if (r < 50) v = A[(size_t)r * K + gk];
        else if (r == 50) v = lastrow[gk];
      }
      As[kk][r] = v;
    }
#pragma unroll
    for (int i = 0; i < 4; ++i) {
      int idx = tid + i * 256;
      int c = idx & 63, kk = idx >> 6;
      int gc = col0 + c, gk = k0 + kk;
      float v = 0.f;
      if (gk < K && gc < Nc) v = W[(size_t)gk * Nc + gc];
      Ws[kk][c] = v;
    }
    __syncthreads();
#pragma unroll
    for (int kk = 0; kk < 16; ++kk) {
      float4 a4 = *(const float4*)&As[kk][ty * 4];
      float4 b4 = *(const float4*)&Ws[kk][tx * 4];
      float av[4] = {a4.x, a4.y, a4.z, a4.w};
      float bv[4] = {b4.x, b4.y, b4.z, b4.w};
#pragma unroll
      for (int i = 0; i < 4; ++i)
#pragma unroll
        for (int j = 0; j < 4; ++j)
          acc[i][j] = fmaf(av[i], bv[j], acc[i][j]);
    }
    __syncthreads();
  }
#pragma unroll
  for (int i = 0; i < 4; ++i) {
    int gr = ty * 4 + i;
    if (gr >= 51) continue;
#pragma unroll
    for (int j = 0; j < 4; ++j) {
      int gc = col0 + tx * 4 + j;
      if (gc >= Nc) continue;
      float v = acc[i][j];
      if (gr == 50) v += bias[gc];
      C[(size_t)gr * Nc + gc] = v;
    }
  }
}

// ---------------------------------------------------------------------------
// Fused stage4 + x-prep kernel. Unchanged.
// ---------------------------------------------------------------------------
__global__ __launch_bounds__(TPB) void fold4_xprep_k(
    const float* __restrict__ aug3,   // [51][768]
    const float* __restrict__ Wruv,   // [768][2304]
    const float* __restrict__ bruv,   // [2304]
    unsigned short* __restrict__ WfTh, unsigned short* __restrict__ WfTl,
    float* __restrict__ bfv,
    const float* __restrict__ x,      // [7688][50]
    unsigned short* __restrict__ xh, unsigned short* __restrict__ xl)
{
  __shared__ float As[16][68];
  __shared__ float Ws[16][68];
  int bid = blockIdx.x;
  int tid = threadIdx.x;

  if (bid >= 36) {
    int row0 = (bid - 36) * 64;
#pragma unroll
    for (int i = 0; i < 16; ++i) {
      int idx = tid + i * 256;
      int row = row0 + (idx >> 6), cc = idx & 63;
      if (row >= 7688) continue;
      float v = (cc < 50) ? x[(size_t)row * 50 + cc] : 0.f;
      unsigned short hi = f2bf(v);
      xh[(size_t)row * 64 + cc] = hi;
      xl[(size_t)row * 64 + cc] = f2bf(v - bf2f(hi));
    }
    return;
  }

  const int K = 768, Nc = 2304;
  const float* lastrow = aug3 + (size_t)50 * 768;
  int col0 = bid * 64;
  int ty = tid >> 4, tx = tid & 15;
  float acc[4][4] = {};
  for (int k0 = 0; k0 < K; k0 += 16) {
#pragma unroll
    for (int i = 0; i < 4; ++i) {
      int idx = tid + i * 256;
      int r = idx >> 4, kk = idx & 15;
      int gk = k0 + kk;
      float v = 0.f;
      if (r < 50) v = aug3[(size_t)r * K + gk];
      else if (r == 50) v = lastrow[gk];
      As[kk][r] = v;
    }
#pragma unroll
    for (int i = 0; i < 4; ++i) {
      int idx = tid + i * 256;
      int c = idx & 63, kk = idx >> 6;
      Ws[kk][c] = Wruv[(size_t)(k0 + kk) * Nc + col0 + c];
    }
    __syncthreads();
#pragma unroll
    for (int kk = 0; kk < 16; ++kk) {
      float4 a4 = *(const float4*)&As[kk][ty * 4];
      float4 b4 = *(const float4*)&Ws[kk][tx * 4];
      float av[4] = {a4.x, a4.y, a4.z, a4.w};
      float bv[4] = {b4.x, b4.y, b4.z, b4.w};
#pragma unroll
      for (int i = 0; i < 4; ++i)
#pragma unroll
        for (int j = 0; j < 4; ++j)
          acc[i][j] = fmaf(av[i], bv[j], acc[i][j]);
    }
    __syncthreads();
  }
#pragma unroll
  for (int i = 0; i < 4; ++i) {
    int gr = ty * 4 + i;
    if (gr >= 51) continue;
#pragma unroll
    for (int j = 0; j < 4; ++j) {
      int gc = col0 + tx * 4 + j;
      float v = acc[i][j];
      if (gr == 50) {
        bfv[gc] = v + bruv[gc];
      } else {
        unsigned short hi = f2bf(v);
        size_t el = (size_t)gc * 64 + gr;       // LINEAR layout
        WfTh[el] = hi;
        WfTl[el] = f2bf(v - bf2f(hi));
      }
    }
  }
}

// ---------------------------------------------------------------------------
// Split-precision MFMA ruv GEMM v3 — no LDS, no barriers. Unchanged.
// ---------------------------------------------------------------------------
__global__ __launch_bounds__(TPB) void gemm_ruv_mfma_k(
    const unsigned short* __restrict__ xh,    // [7688+64][64] bf16
    const unsigned short* __restrict__ xl,
    const unsigned short* __restrict__ WfTh,  // [2304][64] bf16 linear
    const unsigned short* __restrict__ WfTl,
    const float* __restrict__ bias,           // [2304] fp32
    unsigned short* __restrict__ RU,          // [7688][1536]
    unsigned short* __restrict__ Vt)          // [hb][64][968], hb=h*8+b
{
  int tid = threadIdx.x, w = tid >> 6, lane = tid & 63;
  int g = lane >> 4, c = lane & 15;
  int by = blockIdx.y;
  int b = by >> 4, nb = by & 15;
  int m0 = b * 961 + nb * 64;
  int n0base = nb * 64;
  int col0 = blockIdx.x * 256;
  int wc0 = w * 64;

  bf16x8 afh[4][2], afl[4][2];
#pragma unroll
  for (int rt = 0; rt < 4; ++rt) {
    size_t rowb = (size_t)(m0 + rt * 16 + c) * 64;
#pragma unroll
    for (int kk = 0; kk < 2; ++kk) {
      afh[rt][kk] = *(const bf16x8*)&xh[rowb + kk * 32 + g * 8];
      afl[rt][kk] = *(const bf16x8*)&xl[rowb + kk * 32 + g * 8];
    }
  }

  f32x4 zero4 = {0.f, 0.f, 0.f, 0.f};
  f32x4 acc[4][4] = {{zero4, zero4, zero4, zero4}, {zero4, zero4, zero4, zero4},
                     {zero4, zero4, zero4, zero4}, {zero4, zero4, zero4, zero4}};

#pragma unroll
  for (int ct = 0; ct < 4; ++ct) {
    size_t bcolb = (size_t)(col0 + wc0 + ct * 16 + c) * 64;
    bf16x8 bh0 = *(const bf16x8*)&WfTh[bcolb + g * 8];
    bf16x8 bh1 = *(const bf16x8*)&WfTh[bcolb + 32 + g * 8];
    bf16x8 bl0 = *(const bf16x8*)&WfTl[bcolb + g * 8];
    bf16x8 bl1 = *(const bf16x8*)&WfTl[bcolb + 32 + g * 8];
#pragma unroll
    for (int rt = 0; rt < 4; ++rt) {
      acc[rt][ct] = MFMA16(afh[rt][0], bh0, acc[rt][ct]);
      acc[rt][ct] = MFMA16(afh[rt][1], bh1, acc[rt][ct]);
      acc[rt][ct] = MFMA16(afl[rt][0], bh0, acc[rt][ct]);
      acc[rt][ct] = MFMA16(afl[rt][1], bh1, acc[rt][ct]);
      acc[rt][ct] = MFMA16(afh[rt][0], bl0, acc[rt][ct]);
      acc[rt][ct] = MFMA16(afh[rt][1], bl1, acc[rt][ct]);
    }
  }

  bool isRU = (col0 < 1536);
#pragma unroll
  for (int ct = 0; ct < 4; ++ct) {
    int col = col0 + wc0 + ct * 16 + c;
    float bs = bias[col];
    if (isRU) {
#pragma unroll
      for (int rt = 0; rt < 4; ++rt) {
        int lr0 = rt * 16 + g * 4;
#pragma unroll
        for (int r = 0; r < 4; ++r) {
          int n = n0base + lr0 + r;
          if (n <= 960)
            RU[(size_t)(m0 + lr0 + r) * 1536 + col] = f2bf(acc[rt][ct][r] + bs);
        }
      }
    } else {
      int hd = col - 1536;
      int hh = hd >> 6, d = hd & 63;
      size_t vrow = ((size_t)(hh * 8 + b) * 64 + d) * 968;
#pragma unroll
      for (int rt = 0; rt < 4; ++rt) {
        int n0 = n0base + rt * 16 + g * 4;
        if (n0 + 3 <= 960) {
          ushort4 o;
          o.x = f2bf(acc[rt][ct][0] + bs);
          o.y = f2bf(acc[rt][ct][1] + bs);
          o.z = f2bf(acc[rt][ct][2] + bs);
          o.w = f2bf(acc[rt][ct][3] + bs);
          *(ushort4*)&Vt[vrow + n0] = o;
        } else {
#pragma unroll
          for (int r = 0; r < 4; ++r) {
            int n = n0 + r;
            if (n <= 960) Vt[vrow + n] = f2bf(acc[rt][ct][r] + bs);
          }
        }
      }
    }
  }
}

// ---------------------------------------------------------------------------
// Standalone fold: wfold[m] = Wp1[m,:].Wp2 (grid 7689 x 512).
// Block 7688 additionally initializes out[0..95] = bp1.Wp2 + bp2.
// ---------------------------------------------------------------------------
__global__ __launch_bounds__(512) void fold_wp_init_k(
    const float* __restrict__ Wp1, const float* __restrict__ Wp2,
    float* __restrict__ wfold,
    const float* __restrict__ bp1, const float* __restrict__ bp2,
    float* __restrict__ out)
{
  __shared__ float w2[1536];
  __shared__ float red[8];
  int bid = blockIdx.x;
  int tid = threadIdx.x;
  int wv = tid >> 6, lane = tid & 63;

  if (bid == 7688) {
    // out init: const = bp1 . Wp2 + bp2
    float s = 0.f;
    for (int i = tid; i < 1536; i += 512) s += bp1[i] * Wp2[i];
#pragma unroll
    for (int off = 32; off >= 1; off >>= 1) s += __shfl_xor(s, off, 64);
    if (lane == 0) red[wv] = s;
    __syncthreads();
    if (tid < 96) {
      float tot = red[0] + red[1] + red[2] + red[3] +
                  red[4] + red[5] + red[6] + red[7] + bp2[0];
      out[tid] = tot;
    }
    return;
  }

  for (int i = tid; i < 1536; i += 512) w2[i] = Wp2[i];
  __syncthreads();
  int m = bid * 8 + wv;                       // < 61504
  const float* row = Wp1 + (size_t)m * 1536;
  float s = 0.f;
#pragma unroll
  for (int k = 0; k < 6; ++k) {
    float4 a  = *(const float4*)(row + k * 256 + lane * 4);
    float4 ww = *(const float4*)&w2[k * 256 + lane * 4];
    s += a.x * ww.x + a.y * ww.y + a.z * ww.z + a.w * ww.w;
  }
#pragma unroll
  for (int off = 32; off >= 1; off >>= 1) s += __shfl_xor(s, off, 64);
  if (lane == 0) wfold[m] = s;
}

// ---------------------------------------------------------------------------
// Standalone MFMA flash attention with FUSED final projection:
// out[b*12+h] += sum over this block's rows of (o . wfold-segment).
// Internals identical to r13 (dbuf K/V, 1 barrier/tile, ones-MFMA rowsum).
// Grid 768 x 512.
// ---------------------------------------------------------------------------
__global__ __launch_bounds__(512) void attn_final_k(
    const unsigned short* __restrict__ RU,
    const unsigned short* __restrict__ Vt,
    const float* __restrict__ wfold,
    float* __restrict__ out)
{
  __shared__ unsigned short sh[24576];       // 48 KB
  int bid = blockIdx.x;
  int tid = threadIdx.x;

  const int NS = 961, RS = 1536, VROW = 968;
  int qb = bid & 7, hb = bid >> 3;
  int h = hb >> 3, b = hb & 7;
  int n0 = qb * 128;
  int w = tid >> 6, lane = tid & 63;
  int g = lane >> 4, c = lane & 15;
  const unsigned short* rubase = RU + (size_t)b * NS * RS;
  int roff = h * 64, uoff = 768 + h * 64;
  const unsigned short* vtbase = Vt + (size_t)hb * 64 * VROW;
  unsigned short* Kbuf[2] = {sh, sh + 4096};
  unsigned short* Vbuf[2] = {sh + 8192, sh + 12288};
  unsigned short* pw = sh + 16384 + w * 1024;

  int qrow = n0 + w * 16 + c;
  if (qrow > 960) qrow = 960;
  bf16x8 qf0 = *(const bf16x8*)(rubase + (size_t)qrow * RS + roff + g * 8);
  bf16x8 qf1 = *(const bf16x8*)(rubase + (size_t)qrow * RS + roff + 32 + g * 8);

  bf16x8 ones;
#pragma unroll
  for (int i = 0; i < 8; ++i) ones[i] = (short)0x3F80;  // bf16 1.0

  int srow = tid >> 3, ss = tid & 7;
  int sel = srow * 64 + 8 * (ss ^ (srow & 7));
  const unsigned short* ksrc = rubase + uoff + ss * 8;
  const unsigned short* vsrc = vtbase + (size_t)srow * VROW + ss * 8;

  {
    int4 kv = *(const int4*)(ksrc + (size_t)srow * RS);
    int4 vv = *(const int4*)(vsrc);
    *(int4*)&Kbuf[0][sel] = kv;
    *(int4*)&Vbuf[0][sel] = vv;
  }
  __syncthreads();

  f32x4 zero4 = {0.f, 0.f, 0.f, 0.f};
  f32x4 oacc[4] = {zero4, zero4, zero4, zero4};
  f32x4 rowacc = zero4;                      // denominator via ones-MFMA

  unsigned short* Kc = Kbuf[0];
  unsigned short* Vc = Vbuf[0];
  unsigned short* Kn = Kbuf[1];
  unsigned short* Vn = Vbuf[1];

  for (int kt = 0; kt < 16; ++kt) {
    int4 pk, pv;
    bool pre = (kt < 15);
    if (pre) {
      int keyg = (kt + 1) * 64 + srow;
      int kcl = keyg > 960 ? 960 : keyg;
      pk = *(const int4*)(ksrc + (size_t)kcl * RS);
      pv = *(const int4*)(vsrc + (kt + 1) * 64);
    }

    f32x4 sa[4] = {zero4, zero4, zero4, zero4};
    __builtin_amdgcn_s_setprio(1);
#pragma unroll
    for (int ct = 0; ct < 4; ++ct) {
      int key = c * 4 + ct;
      int sw = (key & 7) * 8;
      bf16x8 k0 = *(const bf16x8*)&Kc[key * 64 + ((g * 8) ^ sw)];
      bf16x8 k1 = *(const bf16x8*)&Kc[key * 64 + ((32 + g * 8) ^ sw)];
      sa[ct] = MFMA16(qf0, k0, sa[ct]);
      sa[ct] = MFMA16(qf1, k1, sa[ct]);
    }
    __builtin_amdgcn_s_setprio(0);

    if (kt < 15) {
#pragma unroll
      for (int r = 0; r < 4; ++r) {
        unsigned short pb[4];
#pragma unroll
        for (int ct = 0; ct < 4; ++ct)
          pb[ct] = f2bf(__expf(sa[ct][r]));
        int q = g * 4 + r;
        int e0 = (c * 4) ^ ((q & 7) * 8);
        *(unsigned int*)&pw[q * 64 + e0] =
            (unsigned int)pb[0] | ((unsigned int)pb[1] << 16);
        *(unsigned int*)&pw[q * 64 + e0 + 2] =
            (unsigned int)pb[2] | ((unsigned int)pb[3] << 16);
      }
    } else {
#pragma unroll
      for (int r = 0; r < 4; ++r) {
        unsigned short pb[4];
#pragma unroll
        for (int ct = 0; ct < 4; ++ct) {
          int keyg = kt * 64 + c * 4 + ct;
          pb[ct] = (keyg <= 960) ? f2bf(__expf(sa[ct][r])) : (unsigned short)0;
        }
        int q = g * 4 + r;
        int e0 = (c * 4) ^ ((q & 7) * 8);
        *(unsigned int*)&pw[q * 64 + e0] =
            (unsigned int)pb[0] | ((unsigned int)pb[1] << 16);
        *(unsigned int*)&pw[q * 64 + e0 + 2] =
            (unsigned int)pb[2] | ((unsigned int)pb[3] << 16);
      }
    }

    if (pre) {
      *(int4*)&Kn[sel] = pk;
      *(int4*)&Vn[sel] = pv;
    }

    __builtin_amdgcn_s_setprio(1);
#pragma unroll
    for (int kk = 0; kk < 2; ++kk) {
      bf16x8 pa = *(const bf16x8*)&pw[c * 64 + ((kk * 32 + g * 8) ^ ((c & 7) * 8))];
      rowacc = MFMA16(pa, ones, rowacc);     // denominator, consistent with PV
#pragma unroll
      for (int dt = 0; dt < 4; ++dt) {
        int d = dt * 16 + c;
        bf16x8 vf = *(const bf16x8*)&Vc[d * 64 + ((kk * 32 + g * 8) ^ ((d & 7) * 8))];
        oacc[dt] = MFMA16(pa, vf, oacc[dt]);
      }
    }
    __builtin_amdgcn_s_setprio(0);

    __syncthreads();
    unsigned short* t;
    t = Kc; Kc = Kn; Kn = t;
    t = Vc; Vc = Vn; Vn = t;
  }

  // ---- fused final: part = sum over this thread's (n,d) of o * wfold ----
  int nbase = n0 + w * 16 + g * 4;
  float part = 0.f;
#pragma unroll
  for (int r = 0; r < 4; ++r) {
    int n = nbase + r;
    if (n > 960) continue;
    float inv = 1.f / rowacc[r];
#pragma unroll
    for (int dt = 0; dt < 4; ++dt)
      part += oacc[dt][r] * inv * wfold[(size_t)n * 64 + dt * 16 + c];
  }
  // reduce 512 threads -> 1 atomic
#pragma unroll
  for (int off = 32; off >= 1; off >>= 1) part += __shfl_xor(part, off, 64);
  float* red = (float*)sh;                   // safe: loop ended with barrier
  if (lane == 0) red[w] = part;
  __syncthreads();
  if (tid == 0) {
    float tot = red[0] + red[1] + red[2] + red[3] +
                red[4] + red[5] + red[6] + red[7];
    atomicAdd(&out[b * 12 + h], tot);
  }
}

// ---------------------------------------------------------------------------
extern "C" void kernel_launch(void* const* d_in, const int* in_sizes, int n_in,
                              void* d_out, int out_size, void* d_ws, size_t ws_size,
                              hipStream_t stream)
{
  const float* x    = (const float*)d_in[0];
  const float* W1   = (const float*)d_in[1];
  const float* b1   = (const float*)d_in[2];
  const float* W2   = (const float*)d_in[3];
  const float* b2   = (const float*)d_in[4];
  const float* W3   = (const float*)d_in[5];
  const float* b3   = (const float*)d_in[6];
  const float* W4   = (const float*)d_in[7];
  const float* b4   = (const float*)d_in[8];
  const float* Wruv = (const float*)d_in[9];
  const float* bruv = (const float*)d_in[10];
  const float* Wp1  = (const float*)d_in[11];
  const float* bp1  = (const float*)d_in[12];
  const float* Wp2  = (const float*)d_in[13];
  const float* bp2  = (const float*)d_in[14];
  float* out = (float*)d_out;

  char* base = (char*)d_ws;
  size_t off = 0;
  auto alloc = [&](size_t bytes) -> void* {
    void* p = base + off;
    off = (off + bytes + 255) & ~(size_t)255;
    return p;
  };
  unsigned short* RU  = (unsigned short*)alloc((size_t)7688 * 1536 * 2);          // 23.6 MB
  unsigned short* Vt  = (unsigned short*)alloc((size_t)96 * 64 * 968 * 2 + 1024); // 11.9 MB
  float* aug1  = (float*)alloc(51 * 200 * 4);
  float* aug2  = (float*)alloc(51 * 200 * 4);
  float* aug3  = (float*)alloc(51 * 768 * 4);
  unsigned short* WfTh = (unsigned short*)alloc((size_t)2304 * 64 * 2);
  unsigned short* WfTl = (unsigned short*)alloc((size_t)2304 * 64 * 2);
  unsigned short* xh   = (unsigned short*)alloc((size_t)(7688 + 64) * 64 * 2);    // ~1 MB
  unsigned short* xl   = (unsigned short*)alloc((size_t)(7688 + 64) * 64 * 2);
  float* bfv   = (float*)alloc(2304 * 4);
  float* wfold = (float*)alloc(61504 * 4);
  if (off > ws_size) return;

  dim3 tb(TPB);

  // ---- fold MLP chain (stages 1-3, fp32 augmented) ----
  gemm_fold_k<<<dim3(4),  tb, 0, stream>>>(W1,   b1,            W2, b2, aug1, 200, 200);
  gemm_fold_k<<<dim3(4),  tb, 0, stream>>>(aug1, aug1 + 50*200, W3, b3, aug2, 200, 200);
  gemm_fold_k<<<dim3(12), tb, 0, stream>>>(aug2, aug2 + 50*200, W4, b4, aug3, 200, 768);

  // ---- stage4 (-> WfTh/WfTl/bfv) fused with x split-prep (-> xh/xl) ----
  fold4_xprep_k<<<dim3(157), tb, 0, stream>>>(aug3, Wruv, bruv, WfTh, WfTl, bfv, x, xh, xl);

  // ---- ruv = x @ Wf + bf (split-bf16 MFMA, no-LDS v3) -> RU + Vt ----
  gemm_ruv_mfma_k<<<dim3(9, 128), tb, 0, stream>>>(xh, xl, WfTh, WfTl, bfv, RU, Vt);

  // ---- fold Wp1@Wp2 + out init (standalone, before attention) ----
  fold_wp_init_k<<<dim3(7689), dim3(512), 0, stream>>>(Wp1, Wp2, wfold, bp1, bp2, out);

  // ---- attention with fused final projection (standalone, measurable) ----
  attn_final_k<<<dim3(768), dim3(512), 0, stream>>>(RU, Vt, wfold, out);
}